// Round 1
// baseline (118.396 us; speedup 1.0000x reference)
//
#include <hip/hip_runtime.h>

// Problem constants (from reference): IMG=512, CUT_SIZE=224, CUTN=64, B=4, C=3
constexpr int S  = 224;
constexpr int B  = 4;
constexpr int C  = 3;
constexpr int H  = 512;
constexpr int W  = 512;
constexpr int N  = 64;
constexpr int TOTAL     = N * B * C * S * S;   // 38,535,168
constexpr int TOTAL_VEC = TOTAL / 4;           // 9,633,792 (S*S divisible by 4, rows of 224 too)

__global__ __launch_bounds__(256) void cutouts_kernel(
    const float* __restrict__ x,
    const int*   __restrict__ sizes,
    const int*   __restrict__ offx,
    const int*   __restrict__ offy,
    float*       __restrict__ out)
{
    const int stride = gridDim.x * blockDim.x;
    for (int v = blockIdx.x * blockDim.x + threadIdx.x; v < TOTAL_VEC; v += stride) {
        const int p    = v * 4;
        const int j    = p % S;            // multiple of 4, all 4 pixels in same row
        const int rest = p / S;            // ((n*B+b)*C + c)*S + i
        const int i    = rest % S;
        const int img  = rest / S;         // (n*B+b)*C + c
        const int c    = img % C;
        const int nb   = img / C;          // n*B + b
        const int b    = nb % B;
        const int n    = nb / B;

        const int   sz    = sizes[n];
        const float scale = (float)sz * (1.0f / (float)S);

        // vertical interpolation params (frac BEFORE clamp, like the reference)
        const float sy  = fmaxf(scale * ((float)i + 0.5f) - 0.5f, 0.0f);
        const float fiy = floorf(sy);
        const float fy  = sy - fiy;
        const int   iy0 = min((int)fiy, sz - 1);
        const int   iy1 = min(iy0 + 1, sz - 1);

        const float* base = x + (size_t)((b * C + c) * H) * W;
        const float* row0 = base + (size_t)(offy[n] + iy0) * W;
        const float* row1 = base + (size_t)(offy[n] + iy1) * W;
        const int    ox   = offx[n];

        float4 res;
        float* rp = reinterpret_cast<float*>(&res);
        #pragma unroll
        for (int k = 0; k < 4; ++k) {
            const float sx  = fmaxf(scale * ((float)(j + k) + 0.5f) - 0.5f, 0.0f);
            const float fix = floorf(sx);
            const float fx  = sx - fix;
            const int   ix0 = min((int)fix, sz - 1);
            const int   ix1 = min(ix0 + 1, sz - 1);

            const float v00 = row0[ox + ix0];
            const float v01 = row0[ox + ix1];
            const float v10 = row1[ox + ix0];
            const float v11 = row1[ox + ix1];

            const float top = v00 + (v01 - v00) * fx;   // (1-fx)*v00 + fx*v01
            const float bot = v10 + (v11 - v10) * fx;
            rp[k] = top + (bot - top) * fy;
        }
        *reinterpret_cast<float4*>(out + p) = res;
    }
}

extern "C" void kernel_launch(void* const* d_in, const int* in_sizes, int n_in,
                              void* d_out, int out_size, void* d_ws, size_t ws_size,
                              hipStream_t stream) {
    const float* x     = (const float*)d_in[0];
    const int*   sizes = (const int*)d_in[1];
    const int*   offx  = (const int*)d_in[2];
    const int*   offy  = (const int*)d_in[3];
    // d_in[4] = cut_size (224) — compile-time constant S

    float* out = (float*)d_out;

    const int block = 256;
    int grid = (TOTAL_VEC + block - 1) / block;
    if (grid > 2048) grid = 2048;          // grid-stride the rest
    cutouts_kernel<<<grid, block, 0, stream>>>(x, sizes, offx, offy, out);
}